// Round 11
// baseline (516.542 us; speedup 1.0000x reference)
//
#include <hip/hip_runtime.h>

// Problem constants
#define B_  64
#define T_  2048
#define X_  256

// scan chunking: emit length L and warmup W (||A^16|| ~ 3e-4 << bf16 noise)
#define SCAN_L 16
#define SCAN_W 16

typedef __bf16 bf16x8 __attribute__((ext_vector_type(8)));
typedef float  f32x4  __attribute__((ext_vector_type(4)));

__device__ __forceinline__ unsigned short f2bf(float v) {
  unsigned int x = __float_as_uint(v);
  x += 0x7fffu + ((x >> 16) & 1u);   // RNE
  return (unsigned short)(x >> 16);
}
__device__ __forceinline__ float bf2f(unsigned short s) {
  return __uint_as_float(((unsigned int)s) << 16);
}
__device__ __forceinline__ unsigned int pack2(float a, float b) {
  return (unsigned int)f2bf(a) | ((unsigned int)f2bf(b) << 16);
}

// LDS-only barrier (waits LDS ops, skips the vmcnt(0) drain of __syncthreads)
__device__ __forceinline__ void bar_lds() {
  asm volatile("s_waitcnt lgkmcnt(0)\n\ts_barrier" ::: "memory");
}

__device__ __forceinline__ float sigmoidf(float v) {
  return 1.f / (1.f + __expf(-v));
}

// ---------------------------------------------------------------------------
// Kernel 1 (merged conversions). Head weights fp32->bf16 packed wb:
//   [0)      cy1 256x256 (row-major, as-is)
//   [65536)  cy2 64x256  COLUMN-PERMUTED: wb[.. n*256+p] = cy2[n][ (p>>4) + (p&15)*16 ]
//   [81920)  cz1 256x256 (as-is)
//   [147456) cz2 16x256  COLUMN-PERMUTED same phi
// phi matches the h-store layout in scanheads (K-sum order is free as long as
// A and B agree on the permutation).
// Blocks 592..687: wcat[256][96]=[K_w|Bm_w] bf16; bsum = K_b+Bm_b+A_b.
// ---------------------------------------------------------------------------
__global__ __launch_bounds__(256) void conv_kernel(
    const float* __restrict__ cy1, const float* __restrict__ cy2,
    const float* __restrict__ cz1, const float* __restrict__ cz2,
    const float* __restrict__ Kw, const float* __restrict__ Bw,
    const float* __restrict__ Kb, const float* __restrict__ Bb,
    const float* __restrict__ Ab,
    unsigned short* __restrict__ wb,
    unsigned short* __restrict__ wcat, float* __restrict__ bsum) {
  if (blockIdx.x < 592) {
    int i = blockIdx.x * 256 + threadIdx.x;
    if (i < 65536) {
      wb[i] = f2bf(cy1[i]);
    } else if (i < 81920) {
      int idx = i - 65536, n = idx >> 8, p = idx & 255;
      int lp = (p >> 4) + (p & 15) * 16;
      wb[i] = f2bf(cy2[n * 256 + lp]);
    } else if (i < 147456) {
      wb[i] = f2bf(cz1[i - 81920]);
    } else if (i < 151552) {
      int idx = i - 147456, n = idx >> 8, p = idx & 255;
      int lp = (p >> 4) + (p & 15) * 16;
      wb[i] = f2bf(cz2[n * 256 + lp]);
    }
  } else {
    int k = blockIdx.x - 592;   // 0..95
    int x = threadIdx.x;        // 0..255
    float v = (k < 64) ? Kw[x * 64 + k] : Bw[x * 32 + (k - 64)];
    wcat[x * 96 + k] = f2bf(v);
    if (k == 0) bsum[x] = Kb[x] + Bb[x] + Ab[x];
  }
}

// ---------------------------------------------------------------------------
// Kernel 2: drive via register-blocked MFMA (r8/r10-measured, bit-identical).
// ---------------------------------------------------------------------------
__global__ __launch_bounds__(256) void drive_kernel(
    const float* __restrict__ y, const float* __restrict__ u,
    const unsigned short* __restrict__ wcat, const float* __restrict__ bsum,
    unsigned short* __restrict__ drv) {
  __shared__ __align__(16) unsigned short cat[64 * 104];  // 96 + 8 pad
  __shared__ __align__(16) unsigned short ot[64 * 264];
  const int tid = threadIdx.x;
  const int t   = blockIdx.x;

#pragma unroll
  for (int it = 0; it < 4; it++) {
    int ch = it * 256 + tid;
    int row = ch >> 4, c4 = (ch & 15) * 4;
    float4 v = *(const float4*)(y + ((size_t)row * T_ + t) * 64 + c4);
    uint2 pv; pv.x = pack2(v.x, v.y); pv.y = pack2(v.z, v.w);
    *(uint2*)(cat + row * 104 + c4) = pv;
  }
#pragma unroll
  for (int it = 0; it < 2; it++) {
    int ch = it * 256 + tid;
    int row = ch >> 3, c4 = (ch & 7) * 4;
    float4 v = *(const float4*)(u + ((size_t)row * T_ + t) * 32 + c4);
    uint2 pv; pv.x = pack2(v.x, v.y); pv.y = pack2(v.z, v.w);
    *(uint2*)(cat + row * 104 + 64 + c4) = pv;
  }
  bar_lds();

  const int wv = tid >> 6, lane = tid & 63, lm = lane & 15, quad = lane >> 4;

  bf16x8 bf[4][3];
#pragma unroll
  for (int nt = 0; nt < 4; nt++)
#pragma unroll
    for (int kk = 0; kk < 3; kk++)
      bf[nt][kk] = *(const bf16x8*)(wcat + (size_t)(wv * 64 + nt * 16 + lm) * 96
                                    + kk * 32 + quad * 8);

  f32x4 acc[4][4];   // [nt][m]
#pragma unroll
  for (int nt = 0; nt < 4; nt++)
#pragma unroll
    for (int m = 0; m < 4; m++) acc[nt][m] = (f32x4){0.f, 0.f, 0.f, 0.f};

#pragma unroll
  for (int m = 0; m < 4; m++) {
    bf16x8 af[3];
#pragma unroll
    for (int kk = 0; kk < 3; kk++)
      af[kk] = *(const bf16x8*)(cat + (m * 16 + lm) * 104 + kk * 32 + quad * 8);
#pragma unroll
    for (int nt = 0; nt < 4; nt++)
#pragma unroll
      for (int kk = 0; kk < 3; kk++)
        acc[nt][m] = __builtin_amdgcn_mfma_f32_16x16x32_bf16(af[kk], bf[nt][kk], acc[nt][m], 0, 0, 0);
  }

#pragma unroll
  for (int nt = 0; nt < 4; nt++) {
    int n = wv * 64 + nt * 16 + lm;
    float bias = bsum[n];
#pragma unroll
    for (int m = 0; m < 4; m++)
#pragma unroll
      for (int rg = 0; rg < 4; rg++)
        ot[(m * 16 + quad * 4 + rg) * 264 + n] = f2bf(acc[nt][m][rg] + bias);
  }
  bar_lds();

#pragma unroll
  for (int it = 0; it < 8; it++) {
    int ch = it * 256 + tid, row = ch >> 5, col = (ch & 31) * 8;
    uint4 v = *(const uint4*)(ot + row * 264 + col);
    *(uint4*)(drv + ((size_t)t * B_ + row) * X_ + col) = v;
  }
}

// ---------------------------------------------------------------------------
// Kernel 3 (MEGA: scan + both heads fused; xs intermediate DELETED).
// Block = (chunk, 16-batch group): 512 blocks x 256 thr, 1 barrier/step.
// Per emit step: the scan's bfr frags (lane=batch) double as heads layer1
// A-frags for free. Layer1 C (col=hcol, row=batch) is stored to per-step LDS
// h-buffers COLUMN-PERMUTED (phys = lm*16 + wv*4 + nt -> 4x b64 writes/wave
// instead of 64 scalar b16). Layer2 runs transposed (A = permuted w2 rows,
// B = h rows read b128-contiguous) -> C[col=batch][row=out-n] -> direct
// sigmoid+store of y/z. drv read is the only big input (warmup re-read 2x).
// ---------------------------------------------------------------------------
__global__ __launch_bounds__(256, 1) void scanheads_kernel(
    const unsigned short* __restrict__ drv,   // d' = drive + A_b
    const float* __restrict__ Aw,
    const unsigned short* __restrict__ wb,
    const float* __restrict__ by1, const float* __restrict__ by2,
    const float* __restrict__ bz1, const float* __restrict__ bz2,
    float* __restrict__ yout, float* __restrict__ zout) {
  __shared__ __align__(16) unsigned short Xb[2][16 * 264];
  __shared__ __align__(16) unsigned short Hy[2][16 * 264];
  __shared__ __align__(16) unsigned short Hz[2][16 * 264];
  const int tid = threadIdx.x;
  const int wv = tid >> 6, lane = tid & 63, lm = lane & 15, quad = lane >> 4;
  const int c  = blockIdx.x >> 2;            // chunk 0..127
  const int b0 = (blockIdx.x & 3) * 16;

  const unsigned short* w1y  = wb;            // [256][256]
  const unsigned short* w2yp = wb + 65536;    // [64][256] col-permuted
  const unsigned short* w1z  = wb + 81920;    // [256][256]
  const unsigned short* w2zp = wb + 147456;   // [16][256] col-permuted

  union U8 { bf16x8 v; unsigned short u[8]; uint4 q; };
  // scan A-frags (128 VGPR)
  bf16x8 w[4][8];
#pragma unroll
  for (int mt = 0; mt < 4; mt++) {
#pragma unroll
    for (int kk = 0; kk < 8; kk++) {
      const float* p = Aw + (size_t)((wv * 4 + mt) * 16 + lm) * 256 + kk * 32 + quad * 8;
      float4 a = *(const float4*)p;
      float4 b = *(const float4*)(p + 4);
      U8 tmp;
      tmp.u[0] = f2bf(a.x); tmp.u[1] = f2bf(a.y); tmp.u[2] = f2bf(a.z); tmp.u[3] = f2bf(a.w);
      tmp.u[4] = f2bf(b.x); tmp.u[5] = f2bf(b.y); tmp.u[6] = f2bf(b.z); tmp.u[7] = f2bf(b.w);
      w[mt][kk] = tmp.v;
    }
  }

  // per-lane biases
  float b1yl[4], b1zl[4];
#pragma unroll
  for (int nt = 0; nt < 4; nt++) {
    b1yl[nt] = by1[wv * 64 + nt * 16 + lm];
    b1zl[nt] = bz1[wv * 64 + nt * 16 + lm];
  }
  float4 b2yl = *(const float4*)(by2 + wv * 16 + quad * 4);
  float4 b2zl = *(const float4*)(bz2 + quad * 4);

  {
    unsigned int* xz = (unsigned int*)&Xb[0][0];
    for (int i = tid; i < (16 * 264) / 2; i += 256) xz[i] = 0u;
  }
  bar_lds();

  const int j0 = (c == 0) ? SCAN_W : 0;      // chunk 0 starts exactly at t=0
  int t = c * SCAN_L - SCAN_W + j0;

  int p = 0;
  for (int j = j0; j < SCAN_W + SCAN_L; j++, t++) {
    const bool emit = (j >= SCAN_W);

    // d'(t): issue early, consumed at writeback ~whole step later
    uint2 dcur[4];
    {
      const unsigned short* dp = drv + ((size_t)t * B_ + b0 + lm) * X_ + wv * 64 + quad * 4;
#pragma unroll
      for (int mt = 0; mt < 4; mt++) dcur[mt] = *(const uint2*)(dp + mt * 16);
    }

    // state frags: B-operand for scan AND A-operand for heads layer1
    bf16x8 bfr[8];
    {
      const unsigned short* xb = &Xb[p][0] + lm * 264;
#pragma unroll
      for (int kk = 0; kk < 8; kk++)
        bfr[kk] = *(const bf16x8*)(xb + kk * 32 + quad * 8);
    }

    // scan MFMAs: acc = A x_t
    f32x4 acc[4];
#pragma unroll
    for (int mt = 0; mt < 4; mt++) acc[mt] = (f32x4){0.f, 0.f, 0.f, 0.f};
#pragma unroll
    for (int mt = 0; mt < 4; mt++)
#pragma unroll
      for (int kk = 0; kk < 8; kk++)
        acc[mt] = __builtin_amdgcn_mfma_f32_16x16x32_bf16(w[mt][kk], bfr[kk], acc[mt], 0, 0, 0);

    if (emit) {
      // ---- heads layer 1 (wave wv owns hcols [64wv, 64wv+64) per head) ----
      f32x4 ay[4], az[4];
#pragma unroll
      for (int nt = 0; nt < 4; nt++) {
        ay[nt] = (f32x4){0.f, 0.f, 0.f, 0.f};
        az[nt] = (f32x4){0.f, 0.f, 0.f, 0.f};
      }
#pragma unroll
      for (int kk = 0; kk < 8; kk++) {
        bf16x8 wy[4];
#pragma unroll
        for (int nt = 0; nt < 4; nt++)
          wy[nt] = *(const bf16x8*)(w1y + (size_t)(wv * 64 + nt * 16 + lm) * 256 + kk * 32 + quad * 8);
#pragma unroll
        for (int nt = 0; nt < 4; nt++)
          ay[nt] = __builtin_amdgcn_mfma_f32_16x16x32_bf16(bfr[kk], wy[nt], ay[nt], 0, 0, 0);
      }
#pragma unroll
      for (int kk = 0; kk < 8; kk++) {
        bf16x8 wz[4];
#pragma unroll
        for (int nt = 0; nt < 4; nt++)
          wz[nt] = *(const bf16x8*)(w1z + (size_t)(wv * 64 + nt * 16 + lm) * 256 + kk * 32 + quad * 8);
#pragma unroll
        for (int nt = 0; nt < 4; nt++)
          az[nt] = __builtin_amdgcn_mfma_f32_16x16x32_bf16(bfr[kk], wz[nt], az[nt], 0, 0, 0);
      }
      // epilogue: relu+bias, permuted-packed h store (4x b64 per head)
      // C: row=quad*4+rg = batch, col = hcol nt*16+lm (+64wv); phys col =
      // lm*16 + wv*4 + nt -> nt 0..3 contiguous.
#pragma unroll
      for (int rg = 0; rg < 4; rg++) {
        unsigned int lo, hi;
        lo = pack2(fmaxf(ay[0][rg] + b1yl[0], 0.f), fmaxf(ay[1][rg] + b1yl[1], 0.f));
        hi = pack2(fmaxf(ay[2][rg] + b1yl[2], 0.f), fmaxf(ay[3][rg] + b1yl[3], 0.f));
        *(uint2*)(&Hy[p][0] + (quad * 4 + rg) * 264 + lm * 16 + wv * 4) = (uint2){lo, hi};
        lo = pack2(fmaxf(az[0][rg] + b1zl[0], 0.f), fmaxf(az[1][rg] + b1zl[1], 0.f));
        hi = pack2(fmaxf(az[2][rg] + b1zl[2], 0.f), fmaxf(az[3][rg] + b1zl[3], 0.f));
        *(uint2*)(&Hz[p][0] + (quad * 4 + rg) * 264 + lm * 16 + wv * 4) = (uint2){lo, hi};
      }
    }

    // x writeback: x_{t+1} = A x_t + d'
    {
      unsigned short* xn = &Xb[1 - p][0] + lm * 264 + wv * 64 + quad * 4;
#pragma unroll
      for (int mt = 0; mt < 4; mt++) {
        unsigned int lo = dcur[mt].x, hi = dcur[mt].y;
        float d0 = bf2f((unsigned short)(lo & 0xffff));
        float d1 = bf2f((unsigned short)(lo >> 16));
        float d2 = bf2f((unsigned short)(hi & 0xffff));
        float d3 = bf2f((unsigned short)(hi >> 16));
        uint2 ov;
        ov.x = pack2(acc[mt][0] + d0, acc[mt][1] + d1);
        ov.y = pack2(acc[mt][2] + d2, acc[mt][3] + d3);
        *(uint2*)(xn + mt * 16) = ov;
      }
    }

    bar_lds();

    if (emit) {
      // ---- layer 2 (transposed): A = w2p rows (M = out-n), B = h rows
      // (N = batch). C: col=lm=batch, row=quad*4+rg = out-n. ----
      f32x4 oy = (f32x4){0.f, 0.f, 0.f, 0.f};
#pragma unroll
      for (int kk = 0; kk < 8; kk++) {
        bf16x8 hb = *(const bf16x8*)(&Hy[p][0] + lm * 264 + kk * 32 + quad * 8);
        bf16x8 wa = *(const bf16x8*)(w2yp + (size_t)(wv * 16 + lm) * 256 + kk * 32 + quad * 8);
        oy = __builtin_amdgcn_mfma_f32_16x16x32_bf16(wa, hb, oy, 0, 0, 0);
      }
      {
        float* yo = yout + ((size_t)(b0 + lm) * T_ + t) * 64 + wv * 16 + quad * 4;
        yo[0] = sigmoidf(oy[0] + b2yl.x);
        yo[1] = sigmoidf(oy[1] + b2yl.y);
        yo[2] = sigmoidf(oy[2] + b2yl.z);
        yo[3] = sigmoidf(oy[3] + b2yl.w);
      }
      if (wv == 0) {
        f32x4 oz = (f32x4){0.f, 0.f, 0.f, 0.f};
#pragma unroll
        for (int kk = 0; kk < 8; kk++) {
          bf16x8 hb = *(const bf16x8*)(&Hz[p][0] + lm * 264 + kk * 32 + quad * 8);
          bf16x8 wa = *(const bf16x8*)(w2zp + (size_t)lm * 256 + kk * 32 + quad * 8);
          oz = __builtin_amdgcn_mfma_f32_16x16x32_bf16(wa, hb, oz, 0, 0, 0);
        }
        float* zo = zout + ((size_t)(b0 + lm) * T_ + t) * 16 + quad * 4;
        zo[0] = sigmoidf(oz[0] + b2zl.x);
        zo[1] = sigmoidf(oz[1] + b2zl.y);
        zo[2] = sigmoidf(oz[2] + b2zl.z);
        zo[3] = sigmoidf(oz[3] + b2zl.w);
      }
    }
    p ^= 1;
  }
}

// ---------------------------------------------------------------------------
extern "C" void kernel_launch(void* const* d_in, const int* in_sizes, int n_in,
                              void* d_out, int out_size, void* d_ws, size_t ws_size,
                              hipStream_t stream) {
  const float* y    = (const float*)d_in[0];
  const float* u    = (const float*)d_in[1];
  const float* Aw   = (const float*)d_in[2];
  const float* Ab   = (const float*)d_in[3];
  const float* Kw   = (const float*)d_in[4];
  const float* Kb   = (const float*)d_in[5];
  const float* Bw   = (const float*)d_in[6];
  const float* Bb   = (const float*)d_in[7];
  const float* Cy1w = (const float*)d_in[8];
  const float* Cy1b = (const float*)d_in[9];
  const float* Cy2w = (const float*)d_in[10];
  const float* Cy2b = (const float*)d_in[11];
  const float* Cz1w = (const float*)d_in[12];
  const float* Cz1b = (const float*)d_in[13];
  const float* Cz2w = (const float*)d_in[14];
  const float* Cz2b = (const float*)d_in[15];

  // ws layout (bf16 unless noted): drv [T*B*X] | wb [151552] | wcat [24576] |
  // bsum fp32 [256]   (xs intermediate eliminated by the scan+heads fusion)
  unsigned short* drv  = (unsigned short*)d_ws;
  unsigned short* wb   = drv + (size_t)T_ * B_ * X_;
  unsigned short* wcat = wb + 151552;
  float*          bsum = (float*)(wcat + 24576);

  float* yout = (float*)d_out;
  float* zout = yout + (size_t)B_ * T_ * 64;

  hipLaunchKernelGGL(conv_kernel, dim3(688), dim3(256), 0, stream,
                     Cy1w, Cy2w, Cz1w, Cz2w, Kw, Bw, Kb, Bb, Ab, wb, wcat, bsum);
  hipLaunchKernelGGL(drive_kernel, dim3(T_), dim3(256), 0, stream,
                     y, u, wcat, bsum, drv);
  hipLaunchKernelGGL(scanheads_kernel, dim3((T_ / SCAN_L) * 4), dim3(256), 0, stream,
                     drv, Aw, wb, Cy1b, Cy2b, Cz1b, Cz2b, yout, zout);
}

// Round 12
// 338.813 us; speedup vs baseline: 1.5246x; 1.5246x over previous
//
#include <hip/hip_runtime.h>

// Problem constants
#define B_  64
#define T_  2048
#define X_  256

// scan chunking: emit length L and warmup W (||A^16|| ~ 3e-4 << bf16 noise)
#define SCAN_L 16
#define SCAN_W 16

typedef __bf16 bf16x8 __attribute__((ext_vector_type(8)));
typedef float  f32x4  __attribute__((ext_vector_type(4)));

__device__ __forceinline__ unsigned short f2bf(float v) {
  unsigned int x = __float_as_uint(v);
  x += 0x7fffu + ((x >> 16) & 1u);   // RNE
  return (unsigned short)(x >> 16);
}
__device__ __forceinline__ float bf2f(unsigned short s) {
  return __uint_as_float(((unsigned int)s) << 16);
}
__device__ __forceinline__ unsigned int pack2(float a, float b) {
  return (unsigned int)f2bf(a) | ((unsigned int)f2bf(b) << 16);
}

// LDS-only barrier (waits LDS ops, skips the vmcnt(0) drain of __syncthreads)
__device__ __forceinline__ void bar_lds() {
  asm volatile("s_waitcnt lgkmcnt(0)\n\ts_barrier" ::: "memory");
}

__device__ __forceinline__ float sigmoidf(float v) {
  return 1.f / (1.f + __expf(-v));
}

// ---------------------------------------------------------------------------
// Kernel 1 (merged conversions). Head weights fp32->bf16 packed wb:
//   [0)      cy1 256x256 (as-is)
//   [65536)  cy2 64x256  COL-PERMUTED: wb[n*256+p] = cy2[n][(p>>4) + (p&15)*16]
//   [81920)  cz1 256x256 (as-is)
//   [147456) cz2 16x256  COL-PERMUTED (same phi)
// phi matches the permuted h-store in heads (K-order agreement is all that
// matters). Blocks 592..687: wcat[256][96]=[K_w|Bm_w]; bsum=K_b+Bm_b+A_b.
// ---------------------------------------------------------------------------
__global__ __launch_bounds__(256) void conv_kernel(
    const float* __restrict__ cy1, const float* __restrict__ cy2,
    const float* __restrict__ cz1, const float* __restrict__ cz2,
    const float* __restrict__ Kw, const float* __restrict__ Bw,
    const float* __restrict__ Kb, const float* __restrict__ Bb,
    const float* __restrict__ Ab,
    unsigned short* __restrict__ wb,
    unsigned short* __restrict__ wcat, float* __restrict__ bsum) {
  if (blockIdx.x < 592) {
    int i = blockIdx.x * 256 + threadIdx.x;
    if (i < 65536) {
      wb[i] = f2bf(cy1[i]);
    } else if (i < 81920) {
      int idx = i - 65536, n = idx >> 8, p = idx & 255;
      int lp = (p >> 4) + (p & 15) * 16;
      wb[i] = f2bf(cy2[n * 256 + lp]);
    } else if (i < 147456) {
      wb[i] = f2bf(cz1[i - 81920]);
    } else if (i < 151552) {
      int idx = i - 147456, n = idx >> 8, p = idx & 255;
      int lp = (p >> 4) + (p & 15) * 16;
      wb[i] = f2bf(cz2[n * 256 + lp]);
    }
  } else {
    int k = blockIdx.x - 592;   // 0..95
    int x = threadIdx.x;        // 0..255
    float v = (k < 64) ? Kw[x * 64 + k] : Bw[x * 32 + (k - 64)];
    wcat[x * 96 + k] = f2bf(v);
    if (k == 0) bsum[x] = Kb[x] + Bb[x] + Ab[x];
  }
}

// ---------------------------------------------------------------------------
// Kernel 2: drive via register-blocked MFMA (r8/r10-measured, bit-identical).
// ---------------------------------------------------------------------------
__global__ __launch_bounds__(256) void drive_kernel(
    const float* __restrict__ y, const float* __restrict__ u,
    const unsigned short* __restrict__ wcat, const float* __restrict__ bsum,
    unsigned short* __restrict__ drv) {
  __shared__ __align__(16) unsigned short cat[64 * 104];  // 96 + 8 pad
  __shared__ __align__(16) unsigned short ot[64 * 264];
  const int tid = threadIdx.x;
  const int t   = blockIdx.x;

#pragma unroll
  for (int it = 0; it < 4; it++) {
    int ch = it * 256 + tid;
    int row = ch >> 4, c4 = (ch & 15) * 4;
    float4 v = *(const float4*)(y + ((size_t)row * T_ + t) * 64 + c4);
    uint2 pv; pv.x = pack2(v.x, v.y); pv.y = pack2(v.z, v.w);
    *(uint2*)(cat + row * 104 + c4) = pv;
  }
#pragma unroll
  for (int it = 0; it < 2; it++) {
    int ch = it * 256 + tid;
    int row = ch >> 3, c4 = (ch & 7) * 4;
    float4 v = *(const float4*)(u + ((size_t)row * T_ + t) * 32 + c4);
    uint2 pv; pv.x = pack2(v.x, v.y); pv.y = pack2(v.z, v.w);
    *(uint2*)(cat + row * 104 + 64 + c4) = pv;
  }
  bar_lds();

  const int wv = tid >> 6, lane = tid & 63, lm = lane & 15, quad = lane >> 4;

  bf16x8 bf[4][3];
#pragma unroll
  for (int nt = 0; nt < 4; nt++)
#pragma unroll
    for (int kk = 0; kk < 3; kk++)
      bf[nt][kk] = *(const bf16x8*)(wcat + (size_t)(wv * 64 + nt * 16 + lm) * 96
                                    + kk * 32 + quad * 8);

  f32x4 acc[4][4];   // [nt][m]
#pragma unroll
  for (int nt = 0; nt < 4; nt++)
#pragma unroll
    for (int m = 0; m < 4; m++) acc[nt][m] = (f32x4){0.f, 0.f, 0.f, 0.f};

#pragma unroll
  for (int m = 0; m < 4; m++) {
    bf16x8 af[3];
#pragma unroll
    for (int kk = 0; kk < 3; kk++)
      af[kk] = *(const bf16x8*)(cat + (m * 16 + lm) * 104 + kk * 32 + quad * 8);
#pragma unroll
    for (int nt = 0; nt < 4; nt++)
#pragma unroll
      for (int kk = 0; kk < 3; kk++)
        acc[nt][m] = __builtin_amdgcn_mfma_f32_16x16x32_bf16(af[kk], bf[nt][kk], acc[nt][m], 0, 0, 0);
  }

#pragma unroll
  for (int nt = 0; nt < 4; nt++) {
    int n = wv * 64 + nt * 16 + lm;
    float bias = bsum[n];
#pragma unroll
    for (int m = 0; m < 4; m++)
#pragma unroll
      for (int rg = 0; rg < 4; rg++)
        ot[(m * 16 + quad * 4 + rg) * 264 + n] = f2bf(acc[nt][m][rg] + bias);
  }
  bar_lds();

#pragma unroll
  for (int it = 0; it < 8; it++) {
    int ch = it * 256 + tid, row = ch >> 5, col = (ch & 31) * 8;
    uint4 v = *(const uint4*)(ot + row * 264 + col);
    *(uint4*)(drv + ((size_t)t * B_ + row) * X_ + col) = v;
  }
}

// ---------------------------------------------------------------------------
// Kernel 3: warm-started chunked scan via MFMA (r10-measured, unchanged).
// ---------------------------------------------------------------------------
__global__ __launch_bounds__(256, 1) void scan_kernel(
    const unsigned short* __restrict__ drv,   // d' = drive + A_b
    const float* __restrict__ Aw,
    unsigned short* __restrict__ xs) {
  __shared__ __align__(16) unsigned short Xb[2][16 * 264];
  const int tid = threadIdx.x;
  const int wv = tid >> 6, lane = tid & 63, lm = lane & 15, quad = lane >> 4;
  const int c  = blockIdx.x >> 2;            // chunk 0..127
  const int b0 = (blockIdx.x & 3) * 16;

  union U8 { bf16x8 v; unsigned short u[8]; uint4 q; };
  bf16x8 w[4][8];
#pragma unroll
  for (int mt = 0; mt < 4; mt++) {
#pragma unroll
    for (int kk = 0; kk < 8; kk++) {
      const float* p = Aw + (size_t)((wv * 4 + mt) * 16 + lm) * 256 + kk * 32 + quad * 8;
      float4 a = *(const float4*)p;
      float4 b = *(const float4*)(p + 4);
      U8 tmp;
      tmp.u[0] = f2bf(a.x); tmp.u[1] = f2bf(a.y); tmp.u[2] = f2bf(a.z); tmp.u[3] = f2bf(a.w);
      tmp.u[4] = f2bf(b.x); tmp.u[5] = f2bf(b.y); tmp.u[6] = f2bf(b.z); tmp.u[7] = f2bf(b.w);
      w[mt][kk] = tmp.v;
    }
  }

  {
    unsigned int* xz = (unsigned int*)&Xb[0][0];
    for (int i = tid; i < (16 * 264) / 2; i += 256) xz[i] = 0u;
  }
  bar_lds();

  const int j0 = (c == 0) ? SCAN_W : 0;      // chunk 0 starts exactly at t=0
  int t = c * SCAN_L - SCAN_W + j0;

  uint2 dcur[4];
  {
    const unsigned short* dp = drv + ((size_t)t * B_ + b0 + lm) * X_ + wv * 64 + quad * 4;
#pragma unroll
    for (int mt = 0; mt < 4; mt++) dcur[mt] = *(const uint2*)(dp + mt * 16);
  }

  uint4 em0, em1;           // deferred emit: wave wv stores k-slices 2wv, 2wv+1
  int emt = -1;

  int p = 0;
  for (int j = j0; j < SCAN_W + SCAN_L; j++, t++) {
    if (emt >= 0) {
      unsigned short* ep = xs + ((size_t)emt * B_ + b0 + lm) * X_ + quad * 8;
      *(uint4*)(ep + (2 * wv) * 32)     = em0;
      *(uint4*)(ep + (2 * wv + 1) * 32) = em1;
    }

    uint2 dnext[4];
    {
      int tn = (t + 1 < T_) ? t + 1 : T_ - 1;
      const unsigned short* dp = drv + ((size_t)tn * B_ + b0 + lm) * X_ + wv * 64 + quad * 4;
#pragma unroll
      for (int mt = 0; mt < 4; mt++) dnext[mt] = *(const uint2*)(dp + mt * 16);
    }

    bf16x8 bfr[8];
    {
      const unsigned short* xb = &Xb[p][0] + lm * 264;
#pragma unroll
      for (int kk = 0; kk < 8; kk++)
        bfr[kk] = *(const bf16x8*)(xb + kk * 32 + quad * 8);
    }

    f32x4 acc[4];
#pragma unroll
    for (int mt = 0; mt < 4; mt++) acc[mt] = (f32x4){0.f, 0.f, 0.f, 0.f};
#pragma unroll
    for (int mt = 0; mt < 4; mt++)
#pragma unroll
      for (int kk = 0; kk < 8; kk++)
        acc[mt] = __builtin_amdgcn_mfma_f32_16x16x32_bf16(w[mt][kk], bfr[kk], acc[mt], 0, 0, 0);

    if (j >= SCAN_W) {      // capture pre-update x_t (static reg indices)
      U8 c0, c1;
      c0.v = (wv == 0) ? bfr[0] : (wv == 1) ? bfr[2] : (wv == 2) ? bfr[4] : bfr[6];
      c1.v = (wv == 0) ? bfr[1] : (wv == 1) ? bfr[3] : (wv == 2) ? bfr[5] : bfr[7];
      em0 = c0.q; em1 = c1.q; emt = t;
    }

    {
      unsigned short* xn = &Xb[1 - p][0] + lm * 264 + wv * 64 + quad * 4;
#pragma unroll
      for (int mt = 0; mt < 4; mt++) {
        unsigned int lo = dcur[mt].x, hi = dcur[mt].y;
        float d0 = bf2f((unsigned short)(lo & 0xffff));
        float d1 = bf2f((unsigned short)(lo >> 16));
        float d2 = bf2f((unsigned short)(hi & 0xffff));
        float d3 = bf2f((unsigned short)(hi >> 16));
        uint2 ov;
        ov.x = pack2(acc[mt][0] + d0, acc[mt][1] + d1);
        ov.y = pack2(acc[mt][2] + d2, acc[mt][3] + d3);
        *(uint2*)(xn + mt * 16) = ov;
      }
    }
#pragma unroll
    for (int mt = 0; mt < 4; mt++) dcur[mt] = dnext[mt];
    bar_lds();
    p ^= 1;
  }

  if (emt >= 0) {   // final flush
    unsigned short* ep = xs + ((size_t)emt * B_ + b0 + lm) * X_ + quad * 8;
    *(uint4*)(ep + (2 * wv) * 32)     = em0;
    *(uint4*)(ep + (2 * wv + 1) * 32) = em1;
  }
}

// ---------------------------------------------------------------------------
// Kernel 4 (REWRITTEN): heads with minimal LDS traffic.
// Grid 4096: head = blockIdx>>11 (tile's two head-blocks share an XCD since
// 2048%8==0), tile = blockIdx&2047, rows = 64 batches of timestep t=tile.
// Layer1: A-frags read DIRECT from global xs (no LDS stage, no stage barrier;
// L2/L3-hot), B=w1 rows, 1-ahead prefetch, acc 4x4. Epilogue: permuted-packed
// h (phys col = lm*16+wv*4+nt) -> 16 b64 LDS writes/lane instead of 64 scalar
// b16. ONE barrier. Layer2 transposed (A = col-permuted w2 rows, B = h rows):
// C[col=batch][row=out-n] -> 4-contiguous-float global stores; z-head splits
// layer2 over batch across all 4 waves (balanced). LDS = 33.8 KB (H only).
// ---------------------------------------------------------------------------
__global__ __launch_bounds__(256, 2) void heads_kernel(
    const unsigned short* __restrict__ xs, const unsigned short* __restrict__ wb,
    const float* __restrict__ by1, const float* __restrict__ by2,
    const float* __restrict__ bz1, const float* __restrict__ bz2,
    float* __restrict__ yout, float* __restrict__ zout) {
  __shared__ __align__(16) unsigned short H[64 * 264];
  const int tid  = threadIdx.x;
  const int head = blockIdx.x >> 11;
  const int t    = blockIdx.x & 2047;
  const int r0   = t * 64;

  const int wv = tid >> 6, lane = tid & 63, lm = lane & 15, quad = lane >> 4;
  const unsigned short* w1  = wb + (head ? 81920  : 0);
  const unsigned short* w2p = wb + (head ? 147456 : 65536);
  const float* b1p = head ? bz1 : by1;
  const float* b2p = head ? bz2 : by2;

  // ---- layer 1: h = relu(x @ W1^T + b1); A from global xs ----
  f32x4 acc[4][4];   // [nt][m]
#pragma unroll
  for (int nt = 0; nt < 4; nt++)
#pragma unroll
    for (int m = 0; m < 4; m++) acc[nt][m] = (f32x4){0.f, 0.f, 0.f, 0.f};

  const unsigned short* xb  = xs + (size_t)r0 * X_ + quad * 8;
  const unsigned short* w1b = w1 + (size_t)(wv * 64 + lm) * 256 + quad * 8;

  bf16x8 acur[4], bcur[4];
#pragma unroll
  for (int m = 0; m < 4; m++)
    acur[m] = *(const bf16x8*)(xb + (m * 16 + lm) * X_);
#pragma unroll
  for (int nt = 0; nt < 4; nt++)
    bcur[nt] = *(const bf16x8*)(w1b + nt * 16 * 256);

#pragma unroll
  for (int kk = 0; kk < 8; kk++) {
    bf16x8 anext[4], bnext[4];
    if (kk < 7) {
#pragma unroll
      for (int m = 0; m < 4; m++)
        anext[m] = *(const bf16x8*)(xb + (m * 16 + lm) * X_ + (kk + 1) * 32);
#pragma unroll
      for (int nt = 0; nt < 4; nt++)
        bnext[nt] = *(const bf16x8*)(w1b + nt * 16 * 256 + (kk + 1) * 32);
    }
#pragma unroll
    for (int nt = 0; nt < 4; nt++)
#pragma unroll
      for (int m = 0; m < 4; m++)
        acc[nt][m] = __builtin_amdgcn_mfma_f32_16x16x32_bf16(acur[m], bcur[nt], acc[nt][m], 0, 0, 0);
#pragma unroll
    for (int m = 0; m < 4; m++)  acur[m]  = anext[m];
#pragma unroll
    for (int nt = 0; nt < 4; nt++) bcur[nt] = bnext[nt];
  }

  // epilogue: relu+bias, permuted-packed h (logical col wv*64+nt*16+lm ->
  // phys col lm*16+wv*4+nt; conv pre-permuted w2 to match)
  float b1l[4];
#pragma unroll
  for (int nt = 0; nt < 4; nt++) b1l[nt] = b1p[wv * 64 + nt * 16 + lm];
#pragma unroll
  for (int m = 0; m < 4; m++)
#pragma unroll
    for (int rg = 0; rg < 4; rg++) {
      unsigned int lo = pack2(fmaxf(acc[0][m][rg] + b1l[0], 0.f),
                              fmaxf(acc[1][m][rg] + b1l[1], 0.f));
      unsigned int hi = pack2(fmaxf(acc[2][m][rg] + b1l[2], 0.f),
                              fmaxf(acc[3][m][rg] + b1l[3], 0.f));
      *(uint2*)(H + (m * 16 + quad * 4 + rg) * 264 + lm * 16 + wv * 4) = (uint2){lo, hi};
    }
  bar_lds();   // the only barrier: h visible to all waves

  // ---- layer 2 (transposed): out = sigmoid(h @ W2^T + b2) ----
  if (head == 0) {
    // y: wave wv owns out-n [wv*16, wv*16+16); nb loops 4 batch groups
    f32x4 o[4];
#pragma unroll
    for (int nb = 0; nb < 4; nb++) o[nb] = (f32x4){0.f, 0.f, 0.f, 0.f};
    const unsigned short* w2b = w2p + (size_t)(wv * 16 + lm) * 256 + quad * 8;
#pragma unroll
    for (int kk = 0; kk < 8; kk++) {
      bf16x8 wa = *(const bf16x8*)(w2b + kk * 32);
#pragma unroll
      for (int nb = 0; nb < 4; nb++) {
        bf16x8 hb = *(const bf16x8*)(H + (nb * 16 + lm) * 264 + kk * 32 + quad * 8);
        o[nb] = __builtin_amdgcn_mfma_f32_16x16x32_bf16(wa, hb, o[nb], 0, 0, 0);
      }
    }
    float4 b2l = *(const float4*)(b2p + wv * 16 + quad * 4);
#pragma unroll
    for (int nb = 0; nb < 4; nb++) {
      int bb = nb * 16 + lm;
      float* yo = yout + ((size_t)bb * T_ + t) * 64 + wv * 16 + quad * 4;
      yo[0] = sigmoidf(o[nb][0] + b2l.x);
      yo[1] = sigmoidf(o[nb][1] + b2l.y);
      yo[2] = sigmoidf(o[nb][2] + b2l.z);
      yo[3] = sigmoidf(o[nb][3] + b2l.w);
    }
  } else {
    // z: wave wv owns batch group [wv*16, wv*16+16); all 16 out-n per wave
    f32x4 o = (f32x4){0.f, 0.f, 0.f, 0.f};
    const unsigned short* w2b = w2p + (size_t)lm * 256 + quad * 8;
#pragma unroll
    for (int kk = 0; kk < 8; kk++) {
      bf16x8 wa = *(const bf16x8*)(w2b + kk * 32);
      bf16x8 hb = *(const bf16x8*)(H + (wv * 16 + lm) * 264 + kk * 32 + quad * 8);
      o = __builtin_amdgcn_mfma_f32_16x16x32_bf16(wa, hb, o, 0, 0, 0);
    }
    float4 b2l = *(const float4*)(b2p + quad * 4);
    int bb = wv * 16 + lm;
    float* zo = zout + ((size_t)bb * T_ + t) * 16 + quad * 4;
    zo[0] = sigmoidf(o[0] + b2l.x);
    zo[1] = sigmoidf(o[1] + b2l.y);
    zo[2] = sigmoidf(o[2] + b2l.z);
    zo[3] = sigmoidf(o[3] + b2l.w);
  }
}

// ---------------------------------------------------------------------------
extern "C" void kernel_launch(void* const* d_in, const int* in_sizes, int n_in,
                              void* d_out, int out_size, void* d_ws, size_t ws_size,
                              hipStream_t stream) {
  const float* y    = (const float*)d_in[0];
  const float* u    = (const float*)d_in[1];
  const float* Aw   = (const float*)d_in[2];
  const float* Ab   = (const float*)d_in[3];
  const float* Kw   = (const float*)d_in[4];
  const float* Kb   = (const float*)d_in[5];
  const float* Bw   = (const float*)d_in[6];
  const float* Bb   = (const float*)d_in[7];
  const float* Cy1w = (const float*)d_in[8];
  const float* Cy1b = (const float*)d_in[9];
  const float* Cy2w = (const float*)d_in[10];
  const float* Cy2b = (const float*)d_in[11];
  const float* Cz1w = (const float*)d_in[12];
  const float* Cz1b = (const float*)d_in[13];
  const float* Cz2w = (const float*)d_in[14];
  const float* Cz2b = (const float*)d_in[15];

  // ws layout (bf16 unless noted):
  //   drv [T*B*X] | xs [T*B*X] | wb [151552] | wcat [24576] | bsum fp32 [256]
  unsigned short* drv  = (unsigned short*)d_ws;
  unsigned short* xs   = drv + (size_t)T_ * B_ * X_;
  unsigned short* wb   = xs  + (size_t)T_ * B_ * X_;
  unsigned short* wcat = wb + 151552;
  float*          bsum = (float*)(wcat + 24576);

  float* yout = (float*)d_out;
  float* zout = yout + (size_t)B_ * T_ * 64;

  hipLaunchKernelGGL(conv_kernel, dim3(688), dim3(256), 0, stream,
                     Cy1w, Cy2w, Cz1w, Cz2w, Kw, Bw, Kb, Bb, Ab, wb, wcat, bsum);
  hipLaunchKernelGGL(drive_kernel, dim3(T_), dim3(256), 0, stream,
                     y, u, wcat, bsum, drv);
  hipLaunchKernelGGL(scan_kernel, dim3((T_ / SCAN_L) * 4), dim3(256), 0, stream,
                     drv, Aw, xs);
  hipLaunchKernelGGL(heads_kernel, dim3(4096), dim3(256), 0, stream,
                     xs, wb, Cy1b, Cy2b, Cz1b, Cz2b, yout, zout);
}